// Round 6
// baseline (89.361 us; speedup 1.0000x reference)
//
#include <hip/hip_runtime.h>
#include <hip/hip_bf16.h>

typedef __attribute__((ext_vector_type(8))) short bf16x8;
typedef __attribute__((ext_vector_type(4))) float f32x4;

// exp(v/T - 5) with T=0.2  ==  exp2( (v-1) * 5*log2(e) )
#define EXP_SCALE 7.213475204444817f

__device__ __forceinline__ float fast_exp2(float x) {
#if __has_builtin(__builtin_amdgcn_exp2f)
  return __builtin_amdgcn_exp2f(x);
#else
  return exp2f(x);
#endif
}

__device__ __forceinline__ unsigned short f32_to_bf16(float f) {
  unsigned int u = __float_as_uint(f);
  unsigned int r = (u + 0x7FFFu + ((u >> 16) & 1u)) >> 16;
  return (unsigned short)r;
}

// z is stored SWIZZLED in MFMA-fragment order:
//   shorts addr = tile*2048 + kk*512 + slot*8 + rem
// where tile = row>>4, c = row&15, element e: kk = e>>5, q = (e>>3)&3,
// rem = e&7, slot = q*16 + c. A wave (lane = q*16+c) loads one (tile,kk)
// fragment as one contiguous 1KB global_load_dwordx4.

// Kernel 1: L2-normalize rows -> swizzled bf16 z. Zeroes rowsum[8192]
// (atomic accumulation target) and out[0].
__global__ __launch_bounds__(256) void k_normalize(
    const float* __restrict__ emb_i, const float* __restrict__ emb_j,
    unsigned short* __restrict__ z, float* __restrict__ rowsum,
    float* __restrict__ out)
{
  if (blockIdx.x == 0 && threadIdx.x == 0) out[0] = 0.0f;
  if (threadIdx.x < 4) rowsum[(blockIdx.x << 2) + threadIdx.x] = 0.0f;
  const int w = threadIdx.x >> 6;
  const int lane = threadIdx.x & 63;
  const int row = (blockIdx.x << 2) + w;
  const float* src = (row < 4096) ? (emb_i + row * 128) : (emb_j + (row - 4096) * 128);
  float2 v = reinterpret_cast<const float2*>(src)[lane];
  float ss = v.x * v.x + v.y * v.y;
  #pragma unroll
  for (int m = 1; m < 64; m <<= 1) ss += __shfl_xor(ss, m, 64);
  float rinv = 1.0f / sqrtf(ss);
  ushort2 st;
  st.x = f32_to_bf16(v.x * rinv);
  st.y = f32_to_bf16(v.y * rinv);
  const int e = lane << 1;
  const int kk = e >> 5;
  const int q = (e >> 3) & 3;
  const int rem = e & 7;
  const int tile = row >> 4;
  const int c = row & 15;
  unsigned short* dst = z + tile * 2048 + kk * 512 + ((q << 4) + c) * 8 + rem;
  *reinterpret_cast<ushort2*>(dst) = st;
}

// Kernel 2 (symmetric): cell = 128 rows x 512 cols, launched iff
// rb < 4(ch+1)  -> 544 cells (Sigma 4(ch+1)) = 53% of the full 1024.
// Band cells (rb in [4ch,4ch+3]) cover the diagonal 512x512 blocks fully:
// row-sums only. Strictly-upper cells (rb < 4ch) also compute per-column
// sums over their 128 rows (the transposed region's row-sums) and
// atomicAdd them into rowsum. A staged via LDS into regs a[8][4]; B
// streamed with ping-pong register dbuf; 8 iters of 4 tiles/wave.
// Diagonal exp term (==1 for unit rows) kept; k_finish subtracts 1.
__global__ __launch_bounds__(256, 2) void k_simlse(
    const unsigned short* __restrict__ z,
    float* __restrict__ rowsum,   // [8192], atomic accumulation
    float* __restrict__ rowpos)   // [4096] (row r>=4096 mirrors r-4096)
{
  const int w = threadIdx.x >> 6;
  const int lane = threadIdx.x & 63;
  const int q = lane >> 4;
  const int c = lane & 15;

  // cell id -> (rb, ch): start(ch) = 2ch(ch+1)
  int ch = 0;
  {
    const int b = blockIdx.x;
    while (b >= 2 * (ch + 1) * (ch + 2)) ++ch;
  }
  const int rb = blockIdx.x - 2 * ch * (ch + 1);   // 0 .. 4ch+3
  const int R0 = rb << 7;                          // 128-row block
  const bool upper = (rb < (ch << 2));             // strictly above diagonal band

  // ---- stage A (tiles R0/16 .. +7, 32KB) into LDS, then registers ----
  __shared__ short smem[16384];
  {
    const unsigned short* zA = z + (R0 >> 4) * 2048;
    #pragma unroll
    for (int j = 0; j < 8; ++j) {
      const int v = (j << 8) + threadIdx.x;
      *reinterpret_cast<bf16x8*>(&smem[v << 3]) =
          *reinterpret_cast<const bf16x8*>(zA + (v << 3));
    }
  }
  __syncthreads();
  bf16x8 a[8][4];
  #pragma unroll
  for (int rg = 0; rg < 8; ++rg)
    #pragma unroll
    for (int kk = 0; kk < 4; ++kk)
      a[rg][kk] = *reinterpret_cast<const bf16x8*>(
          &smem[rg * 2048 + kk * 512 + (lane << 3)]);

  float acc[8][4];
  #pragma unroll
  for (int rg = 0; rg < 8; ++rg)
    #pragma unroll
    for (int e = 0; e < 4; ++e) acc[rg][e] = 0.0f;
  float pacc[2][4] = {{0.f,0.f,0.f,0.f},{0.f,0.f,0.f,0.f}};

  __shared__ float colacc[512];
  __shared__ float lsum[4 * 128];
  __shared__ float lpos[4 * 32];

  // wave w walks 16-col tiles ct = 32ch + w + 4i, i = 0..7
  const int ct0 = (ch << 5) + w;
  const unsigned short* bwave = z + ct0 * 2048 + (lane << 3);

  // positive tile base (rb<32 only; for rb>=32 the chunk test always fails)
  const int pos0t = ((R0 + 4096) & 8191) >> 4;
  const int ipb = ((pos0t >> 5) == ch) ? ((pos0t & 31) >> 2) : -99;

  bf16x8 b0[4], b1[4];
  auto ldb = [&](bf16x8 (&dst)[4], int idx) {
    const unsigned short* p = bwave + idx * 8192;   // stride 4 tiles
    dst[0] = *reinterpret_cast<const bf16x8*>(p);
    dst[1] = *reinterpret_cast<const bf16x8*>(p + 512);
    dst[2] = *reinterpret_cast<const bf16x8*>(p + 1024);
    dst[3] = *reinterpret_cast<const bf16x8*>(p + 1536);
  };

  auto process = [&](const bf16x8 (&bb)[4], int i) {
    float colp = 0.0f;
    #pragma unroll
    for (int hb = 0; hb < 2; ++hb) {
      f32x4 cc[4];
      #pragma unroll
      for (int rr = 0; rr < 4; ++rr) cc[rr] = f32x4{0.f, 0.f, 0.f, 0.f};
      #pragma unroll
      for (int kk = 0; kk < 4; ++kk)
        #pragma unroll
        for (int rr = 0; rr < 4; ++rr)
          cc[rr] = __builtin_amdgcn_mfma_f32_16x16x32_bf16(
              a[(hb << 2) + rr][kk], bb[kk], cc[rr], 0, 0, 0);
      #pragma unroll
      for (int rr = 0; rr < 4; ++rr)
        #pragma unroll
        for (int e = 0; e < 4; ++e) {
          float t = fast_exp2(__builtin_fmaf(cc[rr][e], EXP_SCALE, -EXP_SCALE));
          acc[(hb << 2) + rr][e] += t;
          if (upper) colp += t;
        }
      if (i == ipb + hb) {               // rare, wave-uniform
        #pragma unroll
        for (int rr = 0; rr < 4; ++rr) {
          if (rr == w) {
            #pragma unroll
            for (int e = 0; e < 4; ++e)
              if (c == ((q << 2) + e)) pacc[hb][e] = cc[rr][e] * 5.0f;
          }
        }
      }
    }
    if (upper) {                         // column sums over this cell's 128 rows
      colp += __shfl_xor(colp, 16, 64);
      colp += __shfl_xor(colp, 32, 64);
      if (lane < 16)
        colacc[(((i << 2) + w) << 4) + c] = colp;   // tile 4i+w, col c
    }
  };

  ldb(b0, 0);
  #pragma unroll 1
  for (int i = 0; i < 8; i += 2) {
    ldb(b1, i + 1);
    process(b0, i);
    if (i + 2 < 8) ldb(b0, i + 2);
    process(b1, i + 1);
  }

  // Reduce row-sums over the 16 cols per tile (c-group: xor 1,2,4,8)
  #pragma unroll
  for (int m = 1; m < 16; m <<= 1) {
    #pragma unroll
    for (int rg = 0; rg < 8; ++rg)
      #pragma unroll
      for (int e = 0; e < 4; ++e)
        acc[rg][e] += __shfl_xor(acc[rg][e], m, 64);
    #pragma unroll
    for (int hb = 0; hb < 2; ++hb)
      #pragma unroll
      for (int e = 0; e < 4; ++e)
        pacc[hb][e] += __shfl_xor(pacc[hb][e], m, 64);
  }

  if (c == 0) {
    #pragma unroll
    for (int rg = 0; rg < 8; ++rg)
      #pragma unroll
      for (int e = 0; e < 4; ++e)
        lsum[w * 128 + rg * 16 + (q << 2) + e] = acc[rg][e];
    #pragma unroll
    for (int hb = 0; hb < 2; ++hb)
      #pragma unroll
      for (int e = 0; e < 4; ++e)
        lpos[w * 32 + hb * 16 + (q << 2) + e] = pacc[hb][e];
  }
  __syncthreads();

  if (threadIdx.x < 128) {
    const int t = threadIdx.x;
    const int r = R0 + t;
    float s = lsum[t] + lsum[128 + t] + lsum[256 + t] + lsum[384 + t];
    atomicAdd(&rowsum[r], s);
    if (ipb != -99) {                    // this cell owns the positive cols
      const int rg = t >> 4;
      rowpos[r] = lpos[(rg & 3) * 32 + (rg >> 2) * 16 + (t & 15)];
    }
  }
  if (upper) {                           // flush column sums (transposed rows)
    #pragma unroll
    for (int j = 0; j < 2; ++j) {
      const int idx = (j << 8) + threadIdx.x;
      atomicAdd(&rowsum[(ch << 9) + idx], colacc[idx]);
    }
  }
}

// Kernel 3: tot = rowsum - 1 (diagonal term); lse = 5 + log(tot);
// loss = mean(lse - pos). pos for r>=4096 mirrors r-4096 (S symmetric).
__global__ __launch_bounds__(256) void k_finish(
    const float* __restrict__ rowsum, const float* __restrict__ rowpos,
    float* __restrict__ out)
{
  const int r = blockIdx.x * 256 + threadIdx.x;
  float tot = rowsum[r] - 1.0f;
  float v = 5.0f + logf(tot) - rowpos[r & 4095];
  #pragma unroll
  for (int m = 1; m < 64; m <<= 1) v += __shfl_xor(v, m, 64);
  __shared__ float red[4];
  if ((threadIdx.x & 63) == 0) red[threadIdx.x >> 6] = v;
  __syncthreads();
  if (threadIdx.x == 0)
    atomicAdd(out, (red[0] + red[1] + red[2] + red[3]) * (1.0f / 8192.0f));
}

extern "C" void kernel_launch(void* const* d_in, const int* in_sizes, int n_in,
                              void* d_out, int out_size, void* d_ws, size_t ws_size,
                              hipStream_t stream) {
  const float* emb_i = (const float*)d_in[0];
  const float* emb_j = (const float*)d_in[1];
  unsigned short* z = (unsigned short*)d_ws;                       // 2 MB (swizzled)
  float* rowsum = (float*)((char*)d_ws + 8192 * 128 * 2);          // [8192] = 32 KB
  float* rowpos = rowsum + 8192;                                   // [4096] = 16 KB
  float* out = (float*)d_out;

  k_normalize<<<2048, 256, 0, stream>>>(emb_i, emb_j, z, rowsum, out);
  k_simlse<<<544, 256, 0, stream>>>(z, rowsum, rowpos);
  k_finish<<<32, 256, 0, stream>>>(rowsum, rowpos, out);
}

// Round 7
// 78.949 us; speedup vs baseline: 1.1319x; 1.1319x over previous
//
#include <hip/hip_runtime.h>
#include <hip/hip_bf16.h>

typedef __attribute__((ext_vector_type(8))) short bf16x8;
typedef __attribute__((ext_vector_type(4))) float f32x4;

// exp(v/T - 5) with T=0.2  ==  exp2( (v-1) * 5*log2(e) )
#define EXP_SCALE 7.213475204444817f

__device__ __forceinline__ float fast_exp2(float x) {
#if __has_builtin(__builtin_amdgcn_exp2f)
  return __builtin_amdgcn_exp2f(x);
#else
  return exp2f(x);
#endif
}

__device__ __forceinline__ unsigned short f32_to_bf16(float f) {
  unsigned int u = __float_as_uint(f);
  unsigned int r = (u + 0x7FFFu + ((u >> 16) & 1u)) >> 16;
  return (unsigned short)r;
}

// z is stored SWIZZLED in MFMA-fragment order:
//   shorts addr = tile*2048 + kk*512 + slot*8 + rem
// where tile = row>>4, c = row&15, element e: kk = e>>5, q = (e>>3)&3,
// rem = e&7, slot = q*16 + c. A wave (lane = q*16+c) loads one (tile,kk)
// fragment as one contiguous 1KB load.

// Kernel 1: L2-normalize rows -> swizzled bf16 z. Zeroes rowsum[8192]
// (atomic accumulation target) and out[0].
__global__ __launch_bounds__(256) void k_normalize(
    const float* __restrict__ emb_i, const float* __restrict__ emb_j,
    unsigned short* __restrict__ z, float* __restrict__ rowsum,
    float* __restrict__ out)
{
  if (blockIdx.x == 0 && threadIdx.x == 0) out[0] = 0.0f;
  if (threadIdx.x < 4) rowsum[(blockIdx.x << 2) + threadIdx.x] = 0.0f;
  const int w = threadIdx.x >> 6;
  const int lane = threadIdx.x & 63;
  const int row = (blockIdx.x << 2) + w;
  const float* src = (row < 4096) ? (emb_i + row * 128) : (emb_j + (row - 4096) * 128);
  float2 v = reinterpret_cast<const float2*>(src)[lane];
  float ss = v.x * v.x + v.y * v.y;
  #pragma unroll
  for (int m = 1; m < 64; m <<= 1) ss += __shfl_xor(ss, m, 64);
  float rinv = 1.0f / sqrtf(ss);
  ushort2 st;
  st.x = f32_to_bf16(v.x * rinv);
  st.y = f32_to_bf16(v.y * rinv);
  const int e = lane << 1;
  const int kk = e >> 5;
  const int q = (e >> 3) & 3;
  const int rem = e & 7;
  const int tile = row >> 4;
  const int c = row & 15;
  unsigned short* dst = z + tile * 2048 + kk * 512 + ((q << 4) + c) * 8 + rem;
  *reinterpret_cast<ushort2*>(dst) = st;
}

// Kernel 2 (symmetric, small cells): cell = 64 rows x 512 cols, launched
// iff rb < 8(ch+1), ch 0..15 -> 1088 cells (53% of full work, ~4.3/CU).
// Strictly-upper cells (rb < 8ch) also accumulate per-column sums (the
// transposed region's row-sums) and atomicAdd them into rowsum.
// A (64 rows, 16KB) staged via LDS; B streamed ping-pong (8 iters).
// Diagonal exp term (==1 for unit rows) kept; k_finish subtracts 1.
__global__ __launch_bounds__(256, 3) void k_simlse(
    const unsigned short* __restrict__ z,
    float* __restrict__ rowsum,   // [8192], atomic accumulation
    float* __restrict__ rowpos)   // [4096] (row r>=4096 mirrors r-4096)
{
  const int w = threadIdx.x >> 6;
  const int lane = threadIdx.x & 63;
  const int q = lane >> 4;
  const int c = lane & 15;

  // cell id -> (ch, rb): start(ch) = 4ch(ch+1), cells(ch) = 8(ch+1)
  int ch = 0;
  while ((int)blockIdx.x >= 4 * (ch + 1) * (ch + 2)) ++ch;
  const int rb = blockIdx.x - 4 * ch * (ch + 1);   // 0 .. 8ch+7
  const int R0 = rb << 6;                          // 64-row block
  const bool upper = (rb < (ch << 3));             // strictly above diagonal band

  // ---- stage A (tiles R0/16 .. +3, 16KB) into LDS, then registers ----
  __shared__ short smem[8192];          // 16KB
  {
    const unsigned short* zA = z + (R0 >> 4) * 2048;
    #pragma unroll
    for (int j = 0; j < 4; ++j) {
      const int v = (j << 8) + threadIdx.x;        // 0..1023 vec8 chunks
      *reinterpret_cast<bf16x8*>(&smem[v << 3]) =
          *reinterpret_cast<const bf16x8*>(zA + (v << 3));
    }
  }
  __syncthreads();
  bf16x8 a[4][4];
  #pragma unroll
  for (int rg = 0; rg < 4; ++rg)
    #pragma unroll
    for (int kk = 0; kk < 4; ++kk)
      a[rg][kk] = *reinterpret_cast<const bf16x8*>(
          &smem[rg * 2048 + kk * 512 + (lane << 3)]);

  float acc[4][4];
  #pragma unroll
  for (int rg = 0; rg < 4; ++rg)
    #pragma unroll
    for (int e = 0; e < 4; ++e) acc[rg][e] = 0.0f;
  float pacc[4] = {0.f, 0.f, 0.f, 0.f};

  __shared__ float colacc[512];
  __shared__ float lsum[4][64];
  __shared__ float lpos[4][16];

  // wave w walks 16-col tiles ct = 32ch + w + 4i, i = 0..7
  const int ct0 = (ch << 5) + w;
  const unsigned short* bwave = z + ct0 * 2048 + (lane << 3);

  // positive tile: for rows < 4096 it's 4-aligned at pos0t; owned by this
  // cell iff its 32-tile chunk matches. Never matches for rb >= 64.
  const int pos0t = ((R0 + 4096) & 8191) >> 4;
  const int ipb = ((pos0t >> 5) == ch) ? ((pos0t & 31) >> 2) : -99;

  bf16x8 b0[4], b1[4];
  auto ldb = [&](bf16x8 (&dst)[4], int idx) {
    const unsigned short* p = bwave + idx * 8192;   // stride 4 tiles
    dst[0] = *reinterpret_cast<const bf16x8*>(p);
    dst[1] = *reinterpret_cast<const bf16x8*>(p + 512);
    dst[2] = *reinterpret_cast<const bf16x8*>(p + 1024);
    dst[3] = *reinterpret_cast<const bf16x8*>(p + 1536);
  };

  auto process = [&](const bf16x8 (&bb)[4], int i) {
    f32x4 cc[4];
    #pragma unroll
    for (int rr = 0; rr < 4; ++rr) cc[rr] = f32x4{0.f, 0.f, 0.f, 0.f};
    #pragma unroll
    for (int kk = 0; kk < 4; ++kk)
      #pragma unroll
      for (int rr = 0; rr < 4; ++rr)
        cc[rr] = __builtin_amdgcn_mfma_f32_16x16x32_bf16(
            a[rr][kk], bb[kk], cc[rr], 0, 0, 0);
    float colp0 = 0.0f, colp1 = 0.0f;   // two chains to cut dep latency
    #pragma unroll
    for (int rr = 0; rr < 4; ++rr)
      #pragma unroll
      for (int e = 0; e < 4; ++e) {
        float t = fast_exp2(__builtin_fmaf(cc[rr][e], EXP_SCALE, -EXP_SCALE));
        acc[rr][e] += t;
        if (upper) { if (rr & 1) colp1 += t; else colp0 += t; }
      }
    if (upper) {                         // column sums over the 64 rows
      float colp = colp0 + colp1;
      colp += __shfl_xor(colp, 16, 64);
      colp += __shfl_xor(colp, 32, 64);
      if (lane < 16)
        colacc[(((i << 2) + w) << 4) + c] = colp;   // tile 4i+w, col c
    }
    if (i == ipb) {                      // rare, wave-uniform
      #pragma unroll
      for (int rr = 0; rr < 4; ++rr) {
        if (rr == w) {
          #pragma unroll
          for (int e = 0; e < 4; ++e)
            if (c == ((q << 2) + e)) pacc[e] = cc[rr][e] * 5.0f;
        }
      }
    }
  };

  ldb(b0, 0);
  #pragma unroll 1
  for (int i = 0; i < 8; i += 2) {
    ldb(b1, i + 1);
    process(b0, i);
    if (i + 2 < 8) ldb(b0, i + 2);
    process(b1, i + 1);
  }

  // Reduce row-sums over the 16 cols per tile (c-group: xor 1,2,4,8)
  #pragma unroll
  for (int m = 1; m < 16; m <<= 1) {
    #pragma unroll
    for (int rg = 0; rg < 4; ++rg)
      #pragma unroll
      for (int e = 0; e < 4; ++e)
        acc[rg][e] += __shfl_xor(acc[rg][e], m, 64);
    #pragma unroll
    for (int e = 0; e < 4; ++e) pacc[e] += __shfl_xor(pacc[e], m, 64);
  }

  if (c == 0) {
    #pragma unroll
    for (int rg = 0; rg < 4; ++rg)
      #pragma unroll
      for (int e = 0; e < 4; ++e)
        lsum[w][rg * 16 + (q << 2) + e] = acc[rg][e];
    #pragma unroll
    for (int e = 0; e < 4; ++e) lpos[w][(q << 2) + e] = pacc[e];
  }
  __syncthreads();

  if (threadIdx.x < 64) {
    const int t = threadIdx.x;
    float s = lsum[0][t] + lsum[1][t] + lsum[2][t] + lsum[3][t];
    atomicAdd(&rowsum[R0 + t], s);
    if (ipb != -99)                      // this cell owns the positive cols
      rowpos[R0 + t] = lpos[t >> 4][t & 15];
  }
  if (upper) {                           // flush column sums (transposed rows)
    #pragma unroll
    for (int j = 0; j < 2; ++j) {
      const int idx = (j << 8) + threadIdx.x;
      atomicAdd(&rowsum[(ch << 9) + idx], colacc[idx]);
    }
  }
}

// Kernel 3: tot = rowsum - 1 (diagonal term); lse = 5 + log(tot);
// loss = mean(lse - pos). pos for r>=4096 mirrors r-4096 (S symmetric).
__global__ __launch_bounds__(256) void k_finish(
    const float* __restrict__ rowsum, const float* __restrict__ rowpos,
    float* __restrict__ out)
{
  const int r = blockIdx.x * 256 + threadIdx.x;
  float tot = rowsum[r] - 1.0f;
  float v = 5.0f + logf(tot) - rowpos[r & 4095];
  #pragma unroll
  for (int m = 1; m < 64; m <<= 1) v += __shfl_xor(v, m, 64);
  __shared__ float red[4];
  if ((threadIdx.x & 63) == 0) red[threadIdx.x >> 6] = v;
  __syncthreads();
  if (threadIdx.x == 0)
    atomicAdd(out, (red[0] + red[1] + red[2] + red[3]) * (1.0f / 8192.0f));
}

extern "C" void kernel_launch(void* const* d_in, const int* in_sizes, int n_in,
                              void* d_out, int out_size, void* d_ws, size_t ws_size,
                              hipStream_t stream) {
  const float* emb_i = (const float*)d_in[0];
  const float* emb_j = (const float*)d_in[1];
  unsigned short* z = (unsigned short*)d_ws;                       // 2 MB (swizzled)
  float* rowsum = (float*)((char*)d_ws + 8192 * 128 * 2);          // [8192] = 32 KB
  float* rowpos = rowsum + 8192;                                   // [4096] = 16 KB
  float* out = (float*)d_out;

  k_normalize<<<2048, 256, 0, stream>>>(emb_i, emb_j, z, rowsum, out);
  k_simlse<<<1088, 256, 0, stream>>>(z, rowsum, rowpos);
  k_finish<<<32, 256, 0, stream>>>(rowsum, rowpos, out);
}